// Round 7
// baseline (571.066 us; speedup 1.0000x reference)
//
#include <hip/hip_runtime.h>

typedef unsigned short u16;
typedef unsigned int u32;
typedef __attribute__((ext_vector_type(8))) short bfrag;    // 8 bf16
typedef __attribute__((ext_vector_type(16))) float f32x16;  // 32x32 acc

#define GAS __attribute__((address_space(1)))
#define LAS __attribute__((address_space(3)))

__device__ __forceinline__ u16 f2bf(float f) {
  u32 u = __builtin_bit_cast(u32, f);
  u = (u + 0x7fffu + ((u >> 16) & 1u)) >> 16;
  return (u16)u;
}
__device__ __forceinline__ float bf2f(u16 b) {
  u32 u = ((u32)b) << 16;
  return __builtin_bit_cast(float, u);
}

__device__ __forceinline__ void glds16(const u16* src, u16* dst) {
  __builtin_amdgcn_global_load_lds((const GAS unsigned int*)src,
                                   (LAS unsigned int*)dst, 16, 0, 0);
}

// bicubic 3->5 matrix (PyTorch bicubic a=-0.75, align_corners=False), precomputed
__device__ __constant__ float Mb[5][3] = {
  { 1.096f, -0.096f,  0.0f  },
  { 0.612f,  0.46f,  -0.072f},
  { 0.0f,    1.0f,    0.0f  },
  {-0.072f,  0.46f,   0.612f},
  { 0.0f,   -0.096f,  1.096f},
};

// ---------------- Fused prep: blocks [0,1984): xprep ; [1984,10176): att ----------------
__global__ __launch_bounds__(256) void prep_kernel(const float* __restrict__ x,
                                                   u16* __restrict__ xpad,
                                                   float* __restrict__ att) {
  const int bid = blockIdx.x;
  const int t = threadIdx.x;
  if (bid < 1984) {
    // ---- xprep: x (NCHW f32) -> xpad[b][62][64][256] bf16 zero-padded ----
    const int row = bid % 62;
    const int b = bid / 62;
    u16* outrow = xpad + ((size_t)(b * 62 + row)) * 64 * 256;   // [64 col][256 c]
    if (row == 0 || row == 61) {
      uint4 z = {0, 0, 0, 0};
#pragma unroll
      for (int i = 0; i < 8; ++i)
        *reinterpret_cast<uint4*>(outrow + (size_t)(t + i * 256) * 8) = z;
      return;
    }
    const int h = row - 1;
    __shared__ float xs[64 * 62];
    const float* xb = x + ((size_t)b * 256) * 3600 + h * 60;
    for (int cc = 0; cc < 4; ++cc) {
      for (int u = t; u < 960; u += 256) {
        int c = u / 15, seg = u - (u / 15) * 15;
        float4 v = *reinterpret_cast<const float4*>(xb + (size_t)(cc * 64 + c) * 3600 + seg * 4);
        float* d = &xs[c * 62 + seg * 4];
        d[0] = v.x; d[1] = v.y; d[2] = v.z; d[3] = v.w;
      }
      __syncthreads();
      for (int u = t; u < 512; u += 256) {
        int col = u >> 3, slot = u & 7;
        uint4 o = {0, 0, 0, 0};
        if (col >= 1 && col <= 60) {
          int w = col - 1;
          u16 tmp[8];
#pragma unroll
          for (int j = 0; j < 8; ++j) tmp[j] = f2bf(xs[(slot * 8 + j) * 62 + w]);
          o = *reinterpret_cast<uint4*>(tmp);
        }
        *reinterpret_cast<uint4*>(outrow + (size_t)col * 256 + cc * 64 + slot * 8) = o;
      }
      __syncthreads();
    }
    return;
  }
  // ---- att: pooling pyramid -> att (b, 768, 5, 5) ----
  int bc = bid - 1984;            // b*256 + c
  int b = bc >> 8, c = bc & 255;
  const float* xc = x + (size_t)bc * 3600;
  __shared__ float s15[225];
  __shared__ float p3s[9];
  if (t < 225) {
    int i = t / 15, j = t - (t / 15) * 15;
    const float* base = xc + i * 4 * 60 + j * 4;
    float s = 0.f;
#pragma unroll
    for (int r = 0; r < 4; ++r) {
      float4 v = *reinterpret_cast<const float4*>(base + r * 60);
      s += v.x + v.y + v.z + v.w;
    }
    s15[t] = s;
  }
  __syncthreads();
  float a5v = 0.f;
  if (t < 25) {
    int ii = t / 5, jj = t - (t / 5) * 5;
    float s = 0.f;
#pragma unroll
    for (int r = 0; r < 3; ++r)
#pragma unroll
      for (int cc = 0; cc < 3; ++cc) s += s15[(ii * 3 + r) * 15 + jj * 3 + cc];
    a5v = s * (1.f / 144.f);
  }
  if (t >= 64 && t < 73) {
    int i3 = t - 64;
    int pi = i3 / 3, pj = i3 - pi * 3;
    float s = 0.f;
#pragma unroll
    for (int r = 0; r < 5; ++r)
#pragma unroll
      for (int cc = 0; cc < 5; ++cc) s += s15[(pi * 5 + r) * 15 + pj * 5 + cc];
    p3s[i3] = s * (1.f / 400.f);
  }
  __syncthreads();
  float* attb = att + (size_t)b * 768 * 25;
  if (t < 25) {
    attb[(512 + c) * 25 + t] = a5v;                 // a5
    int o = t / 5, qq = t - (t / 5) * 5;            // a3 = M p3 M^T
    float s = 0.f;
#pragma unroll
    for (int i = 0; i < 3; ++i) {
      float mi = Mb[o][i];
#pragma unroll
      for (int j = 0; j < 3; ++j) s += mi * Mb[qq][j] * p3s[i * 3 + j];
    }
    attb[(256 + c) * 25 + t] = s;
  } else if (t == 32) {
    float s = 0.f;
#pragma unroll
    for (int i = 0; i < 9; ++i) s += p3s[i];
    s *= (1.f / 9.f);                               // a1 = global mean
    for (int p = 0; p < 25; ++p) attb[c * 25 + p] = s;
  }
}

// ---------------- Kernel B: routing head -> r (b, 3, 256) ----------------
__global__ __launch_bounds__(256) void route_kernel(
    const float* __restrict__ att, const float* __restrict__ rw1,
    const float* __restrict__ rdw1, const float* __restrict__ rdw2,
    const float* __restrict__ rw2, float* __restrict__ rout) {
  int b = blockIdx.x;
  int t = threadIdx.x;
  __shared__ u16 attS[768 * 25];
  __shared__ float h1[16 * 25];
  __shared__ float h2[16 * 9];
  __shared__ float h3[16];
  const float* attb = att + (size_t)b * 768 * 25;
  for (int i = t; i < 768 * 25; i += 256) attS[i] = f2bf(attb[i]);
  __syncthreads();
  for (int idx = t; idx < 400; idx += 256) {
    int sq = idx / 25, p = idx - (idx / 25) * 25;
    const float* wrow = rw1 + sq * 768;
    float s = 0.f;
    for (int ic = 0; ic < 768; ++ic) s += wrow[ic] * bf2f(attS[ic * 25 + p]);
    h1[idx] = fmaxf(s, 0.f);
  }
  __syncthreads();
  for (int idx = t; idx < 144; idx += 256) {
    int sq = idx / 9, ij = idx - (idx / 9) * 9;
    int i = ij / 3, j = ij - (ij / 3) * 3;
    float s = 0.f;
#pragma unroll
    for (int u = 0; u < 3; ++u)
#pragma unroll
      for (int v = 0; v < 3; ++v)
        s += rdw1[sq * 9 + u * 3 + v] * h1[sq * 25 + (i + u) * 5 + (j + v)];
    h2[idx] = fmaxf(s, 0.f);
  }
  __syncthreads();
  if (t < 16) {
    float s = 0.f;
#pragma unroll
    for (int uv = 0; uv < 9; ++uv) s += rdw2[t * 9 + uv] * h2[t * 9 + uv];
    h3[t] = fmaxf(s, 0.f);
  }
  __syncthreads();
  for (int idx = t; idx < 768; idx += 256) {
    float s = 0.f;
#pragma unroll
    for (int sq = 0; sq < 16; ++sq) s += rw2[idx * 16 + sq] * h3[sq];
    rout[(size_t)b * 768 + idx] = 1.f / (1.f + expf(-s));
  }
}

// ---------------- Kernel C: combine expert weights -> cw bf16 (b,256, k=kt*64+c_loc) ----------------
__global__ __launch_bounds__(256) void cw_kernel(const float* __restrict__ rout,
                                                 const float* __restrict__ we,
                                                 u16* __restrict__ cw) {
  int idx = blockIdx.x * 256 + threadIdx.x;  // (b,o,c)
  if (idx >= 32 * 256 * 256) return;
  int b = idx >> 16;
  int oc = idx & 65535;
  int o = oc >> 8, c = oc & 255;
  float r0 = rout[b * 768 + c];
  float r1 = rout[b * 768 + 256 + c];
  float r2 = rout[b * 768 + 512 + c];
  const size_t ES = (size_t)256 * 256 * 9;
  const float* w0 = we + ((size_t)o * 256 + c) * 9;
  int ctile = c >> 6, c_loc = c & 63;
  u16* dst = cw + ((size_t)(b * 256 + o)) * 2304 + ctile * 576 + c_loc;
#pragma unroll
  for (int tp = 0; tp < 9; ++tp) {
    float f = r0 * w0[tp] + r1 * w0[ES + tp] + r2 * w0[2 * ES + tp];
    dst[tp * 64] = f2bf(f);
  }
}

// ---------------- Kernel D: per-sample implicit-GEMM conv (MFMA 32x32x16 bf16) ----------------
// Block: 256 thr (4 waves, 2m x 2n). Block tile 256 O x 2 rows (128 px).
// Wave tile 128 O x 64 px. LDS 64KB: X [4 rows][64 col][64 c] @0, A [256][64] @16384.
// 2 blocks/CU. A: global->reg (1-tap prefetch)->ds_write. Swizzle sw(v)=(v^(v>>3))&7,
// computed from the FULL column/row index at every read site (not additive!).
__global__ __launch_bounds__(256, 2) void conv_kernel(const u16* __restrict__ xpad,
                                                      const u16* __restrict__ cw,
                                                      float* __restrict__ y) {
  __shared__ __align__(16) u16 smem[32768];   // 64 KB

  const int flat = blockIdx.x;
  const int wg = (flat & 7) * 120 + (flat >> 3);   // bijective XCD swizzle (960 % 8 == 0)
  const int b = wg / 30;
  const int rg = wg - b * 30;
  const int h0 = rg * 2;

  const int t = threadIdx.x;
  const int wave = t >> 6, lane = t & 63;
  const int wm = wave >> 1, wn = wave & 1;        // 2m x 2n
  const int r32 = lane & 31, half = lane >> 5;

  const u16* cwB = cw + (size_t)b * 256 * 2304;
  const u16* xpB = xpad + ((size_t)(b * 62 + h0) * 64) * 256;

  // ---- X staging: 2048 16B-units, pre-swizzled global source, linear LDS dest ----
  int x_src[8];
#pragma unroll
  for (int i = 0; i < 8; ++i) {
    int u = i * 256 + t;
    int row = u >> 9, col = (u >> 3) & 63, sd = u & 7;
    int sw = (col ^ (col >> 3)) & 7;
    x_src[i] = (row * 64 + col) * 256 + ((sd ^ sw) * 8);
  }
  // ---- A staging: 2048 16B-units (FULL 32KB): linear global src, swizzled LDS dst ----
  int a_gsrc[8], a_ldst[8];
#pragma unroll
  for (int i = 0; i < 8; ++i) {
    int u = i * 256 + t;
    int m = u >> 3, sd = u & 7;
    int sw = (m ^ (m >> 3)) & 7;
    a_gsrc[i] = m * 2304 + sd * 8;
    a_ldst[i] = 16384 + m * 64 + ((sd ^ sw) * 8);
  }
  // ---- A fragment read addrs (per mf, full row), ^ (kg<<4) at use ----
  int a_addr[4];
#pragma unroll
  for (int mf = 0; mf < 4; ++mf) {
    int row = wm * 128 + mf * 32 + r32;
    int sw = (row ^ (row >> 3)) & 7;
    a_addr[mf] = 16384 + row * 64 + ((half ^ sw) * 8);
  }
  // ---- B fragment offsets per (kw, nf) with TRUE column rk + nf*32 ----
  int b_coff[3][2];
#pragma unroll
  for (int kw = 0; kw < 3; ++kw)
#pragma unroll
    for (int nf = 0; nf < 2; ++nf) {
      int col = r32 + kw + nf * 32;
      int sw = (col ^ (col >> 3)) & 7;
      b_coff[kw][nf] = col * 64 + ((half ^ sw) * 8);
    }

  f32x16 acc[4][2] = {};
  uint4 rA[8];

  auto loadA = [&](int kt) {
#pragma unroll
    for (int i = 0; i < 8; ++i)
      rA[i] = *reinterpret_cast<const uint4*>(cwB + a_gsrc[i] + kt * 64);
  };
  auto writeA = [&]() {
#pragma unroll
    for (int i = 0; i < 8; ++i)
      *reinterpret_cast<uint4*>(smem + a_ldst[i]) = rA[i];
  };
  auto stageX = [&](int ct) {
#pragma unroll
    for (int i = 0; i < 8; ++i)
      glds16(xpB + x_src[i] + ct * 64, smem + (i * 256 + t) * 8);
  };

  // ---- prologue ----
  loadA(0);
  stageX(0);
  writeA();                              // dep-waits loadA(0)
  __syncthreads();                       // drains glds16 + makes A(0) visible

#pragma unroll 1
  for (int ct = 0; ct < 4; ++ct) {
#pragma unroll
    for (int tap = 0; tap < 9; ++tap) {
      const int kt = ct * 9 + tap;
      const bool haveNext = !(ct == 3 && tap == 8);
      if (haveNext) loadA(kt + 1);       // issue early; covered by MFMA cluster
      const int kh = tap / 3, kw = tap - kh * 3;
      const int rowbase = (wn + kh) * 4096;
      __builtin_amdgcn_s_setprio(1);
#pragma unroll
      for (int kg = 0; kg < 4; ++kg) {
        const int kx = kg << 4;
        bfrag a[4], bb[2];
#pragma unroll
        for (int mf = 0; mf < 4; ++mf)
          a[mf] = *reinterpret_cast<const bfrag*>(smem + (a_addr[mf] ^ kx));
#pragma unroll
        for (int nf = 0; nf < 2; ++nf)
          bb[nf] = *reinterpret_cast<const bfrag*>(smem + ((rowbase + b_coff[kw][nf]) ^ kx));
#pragma unroll
        for (int mf = 0; mf < 4; ++mf)
#pragma unroll
          for (int nf = 0; nf < 2; ++nf)
            acc[mf][nf] = __builtin_amdgcn_mfma_f32_32x32x16_bf16(a[mf], bb[nf], acc[mf][nf], 0, 0, 0);
      }
      __builtin_amdgcn_s_setprio(0);
      __syncthreads();                   // all waves done reading A(kt)/X(ct)
      if (haveNext) {
        if (tap == 8) stageX(ct + 1);    // X buffer free now
        writeA();                        // A(kt+1) -> LDS
        __syncthreads();                 // stage + writes visible
      }
    }
  }

  // ---- epilogue: C/D 32x32: col=lane&31, row=(reg&3)+8*(reg>>2)+4*(lane>>5) ----
  float* yB = y + ((size_t)(b * 256 + wm * 128)) * 3600 + (size_t)(h0 + wn) * 60;
#pragma unroll
  for (int mf = 0; mf < 4; ++mf)
#pragma unroll
    for (int nf = 0; nf < 2; ++nf) {
      int w = nf * 32 + r32;
      if (w < 60) {
#pragma unroll
        for (int g = 0; g < 4; ++g)
#pragma unroll
          for (int rr = 0; rr < 4; ++rr) {
            int o_loc = mf * 32 + g * 8 + half * 4 + rr;
            yB[(size_t)o_loc * 3600 + w] = acc[mf][nf][g * 4 + rr];
          }
      }
    }
}

extern "C" void kernel_launch(void* const* d_in, const int* in_sizes, int n_in,
                              void* d_out, int out_size, void* d_ws, size_t ws_size,
                              hipStream_t stream) {
  const float* x    = (const float*)d_in[0];
  const float* we   = (const float*)d_in[1];
  const float* rw1  = (const float*)d_in[2];
  const float* rdw1 = (const float*)d_in[3];
  const float* rdw2 = (const float*)d_in[4];
  const float* rw2  = (const float*)d_in[5];
  float* y = (float*)d_out;

  char* ws = (char*)d_ws;
  float* att  = (float*)ws;                    // 2,457,600 B
  float* rout = (float*)(ws + 2457600);        //    98,304 B
  u16*   cwp  = (u16*)(ws + 2555904);          // 37,748,736 B
  u16*   xpad = (u16*)(ws + 40304640);         // 65,011,712 B  (total 105,316,352)

  prep_kernel<<<10176, 256, 0, stream>>>(x, xpad, att);
  route_kernel<<<32, 256, 0, stream>>>(att, rw1, rdw1, rdw2, rw2, rout);
  cw_kernel<<<8192, 256, 0, stream>>>(rout, we, cwp);
  conv_kernel<<<960, 256, 0, stream>>>(xpad, cwp, y);
  (void)in_sizes; (void)n_in; (void)out_size; (void)ws_size;
}

// Round 8
// 278.919 us; speedup vs baseline: 2.0474x; 2.0474x over previous
//
#include <hip/hip_runtime.h>

typedef unsigned short u16;
typedef unsigned int u32;
typedef __attribute__((ext_vector_type(8))) short bfrag;    // 8 bf16
typedef __attribute__((ext_vector_type(16))) float f32x16;  // 32x32 acc

#define GAS __attribute__((address_space(1)))
#define LAS __attribute__((address_space(3)))

__device__ __forceinline__ u16 f2bf(float f) {
  u32 u = __builtin_bit_cast(u32, f);
  u = (u + 0x7fffu + ((u >> 16) & 1u)) >> 16;
  return (u16)u;
}
__device__ __forceinline__ float bf2f(u16 b) {
  u32 u = ((u32)b) << 16;
  return __builtin_bit_cast(float, u);
}

__device__ __forceinline__ void glds16(const u16* src, u16* dst) {
  __builtin_amdgcn_global_load_lds((const GAS unsigned int*)src,
                                   (LAS unsigned int*)dst, 16, 0, 0);
}

// bicubic 3->5 matrix (PyTorch bicubic a=-0.75, align_corners=False), precomputed
__device__ __constant__ float Mb[5][3] = {
  { 1.096f, -0.096f,  0.0f  },
  { 0.612f,  0.46f,  -0.072f},
  { 0.0f,    1.0f,    0.0f  },
  {-0.072f,  0.46f,   0.612f},
  { 0.0f,   -0.096f,  1.096f},
};

// ---------------- Fused prep: blocks [0,1984): xprep ; [1984,10176): att ----------------
__global__ __launch_bounds__(256) void prep_kernel(const float* __restrict__ x,
                                                   u16* __restrict__ xpad,
                                                   float* __restrict__ att) {
  const int bid = blockIdx.x;
  const int t = threadIdx.x;
  if (bid < 1984) {
    // ---- xprep: x (NCHW f32) -> xpad[b][62][64][256] bf16 zero-padded ----
    const int row = bid % 62;
    const int b = bid / 62;
    u16* outrow = xpad + ((size_t)(b * 62 + row)) * 64 * 256;   // [64 col][256 c]
    if (row == 0 || row == 61) {
      uint4 z = {0, 0, 0, 0};
#pragma unroll
      for (int i = 0; i < 8; ++i)
        *reinterpret_cast<uint4*>(outrow + (size_t)(t + i * 256) * 8) = z;
      return;
    }
    const int h = row - 1;
    __shared__ float xs[64 * 62];
    const float* xb = x + ((size_t)b * 256) * 3600 + h * 60;
    for (int cc = 0; cc < 4; ++cc) {
      for (int u = t; u < 960; u += 256) {
        int c = u / 15, seg = u - (u / 15) * 15;
        float4 v = *reinterpret_cast<const float4*>(xb + (size_t)(cc * 64 + c) * 3600 + seg * 4);
        float* d = &xs[c * 62 + seg * 4];
        d[0] = v.x; d[1] = v.y; d[2] = v.z; d[3] = v.w;
      }
      __syncthreads();
      for (int u = t; u < 512; u += 256) {
        int col = u >> 3, slot = u & 7;
        uint4 o = {0, 0, 0, 0};
        if (col >= 1 && col <= 60) {
          int w = col - 1;
          u16 tmp[8];
#pragma unroll
          for (int j = 0; j < 8; ++j) tmp[j] = f2bf(xs[(slot * 8 + j) * 62 + w]);
          o = *reinterpret_cast<uint4*>(tmp);
        }
        *reinterpret_cast<uint4*>(outrow + (size_t)col * 256 + cc * 64 + slot * 8) = o;
      }
      __syncthreads();
    }
    return;
  }
  // ---- att: pooling pyramid -> att (b, 768, 5, 5) ----
  int bc = bid - 1984;            // b*256 + c
  int b = bc >> 8, c = bc & 255;
  const float* xc = x + (size_t)bc * 3600;
  __shared__ float s15[225];
  __shared__ float p3s[9];
  if (t < 225) {
    int i = t / 15, j = t - (t / 15) * 15;
    const float* base = xc + i * 4 * 60 + j * 4;
    float s = 0.f;
#pragma unroll
    for (int r = 0; r < 4; ++r) {
      float4 v = *reinterpret_cast<const float4*>(base + r * 60);
      s += v.x + v.y + v.z + v.w;
    }
    s15[t] = s;
  }
  __syncthreads();
  float a5v = 0.f;
  if (t < 25) {
    int ii = t / 5, jj = t - (t / 5) * 5;
    float s = 0.f;
#pragma unroll
    for (int r = 0; r < 3; ++r)
#pragma unroll
      for (int cc = 0; cc < 3; ++cc) s += s15[(ii * 3 + r) * 15 + jj * 3 + cc];
    a5v = s * (1.f / 144.f);
  }
  if (t >= 64 && t < 73) {
    int i3 = t - 64;
    int pi = i3 / 3, pj = i3 - pi * 3;
    float s = 0.f;
#pragma unroll
    for (int r = 0; r < 5; ++r)
#pragma unroll
      for (int cc = 0; cc < 5; ++cc) s += s15[(pi * 5 + r) * 15 + pj * 5 + cc];
    p3s[i3] = s * (1.f / 400.f);
  }
  __syncthreads();
  float* attb = att + (size_t)b * 768 * 25;
  if (t < 25) {
    attb[(512 + c) * 25 + t] = a5v;                 // a5
    int o = t / 5, qq = t - (t / 5) * 5;            // a3 = M p3 M^T
    float s = 0.f;
#pragma unroll
    for (int i = 0; i < 3; ++i) {
      float mi = Mb[o][i];
#pragma unroll
      for (int j = 0; j < 3; ++j) s += mi * Mb[qq][j] * p3s[i * 3 + j];
    }
    attb[(256 + c) * 25 + t] = s;
  } else if (t == 32) {
    float s = 0.f;
#pragma unroll
    for (int i = 0; i < 9; ++i) s += p3s[i];
    s *= (1.f / 9.f);                               // a1 = global mean
    for (int p = 0; p < 25; ++p) attb[c * 25 + p] = s;
  }
}

// ---------------- Kernel B: routing head -> r (b, 3, 256) ----------------
__global__ __launch_bounds__(256) void route_kernel(
    const float* __restrict__ att, const float* __restrict__ rw1,
    const float* __restrict__ rdw1, const float* __restrict__ rdw2,
    const float* __restrict__ rw2, float* __restrict__ rout) {
  int b = blockIdx.x;
  int t = threadIdx.x;
  __shared__ u16 attS[768 * 25];
  __shared__ float h1[16 * 25];
  __shared__ float h2[16 * 9];
  __shared__ float h3[16];
  const float* attb = att + (size_t)b * 768 * 25;
  for (int i = t; i < 768 * 25; i += 256) attS[i] = f2bf(attb[i]);
  __syncthreads();
  for (int idx = t; idx < 400; idx += 256) {
    int sq = idx / 25, p = idx - (idx / 25) * 25;
    const float* wrow = rw1 + sq * 768;
    float s = 0.f;
    for (int ic = 0; ic < 768; ++ic) s += wrow[ic] * bf2f(attS[ic * 25 + p]);
    h1[idx] = fmaxf(s, 0.f);
  }
  __syncthreads();
  for (int idx = t; idx < 144; idx += 256) {
    int sq = idx / 9, ij = idx - (idx / 9) * 9;
    int i = ij / 3, j = ij - (ij / 3) * 3;
    float s = 0.f;
#pragma unroll
    for (int u = 0; u < 3; ++u)
#pragma unroll
      for (int v = 0; v < 3; ++v)
        s += rdw1[sq * 9 + u * 3 + v] * h1[sq * 25 + (i + u) * 5 + (j + v)];
    h2[idx] = fmaxf(s, 0.f);
  }
  __syncthreads();
  if (t < 16) {
    float s = 0.f;
#pragma unroll
    for (int uv = 0; uv < 9; ++uv) s += rdw2[t * 9 + uv] * h2[t * 9 + uv];
    h3[t] = fmaxf(s, 0.f);
  }
  __syncthreads();
  for (int idx = t; idx < 768; idx += 256) {
    float s = 0.f;
#pragma unroll
    for (int sq = 0; sq < 16; ++sq) s += rw2[idx * 16 + sq] * h3[sq];
    rout[(size_t)b * 768 + idx] = 1.f / (1.f + expf(-s));
  }
}

// ---------------- Kernel C: combine expert weights -> cw bf16, k-major layout ----------------
// cw2[b][kt][slot=kg*2+half][o][e]: kt=ct*9+tap (ct=c>>6), c_loc=c&63,
// kg=c_loc>>4, half=(c_loc>>3)&1, e=c_loc&7. 16B per (slot,o) = one lane's A operand.
__global__ __launch_bounds__(256) void cw_kernel(const float* __restrict__ rout,
                                                 const float* __restrict__ we,
                                                 u16* __restrict__ cw) {
  int idx = blockIdx.x * 256 + threadIdx.x;  // (b,o,c)
  if (idx >= 32 * 256 * 256) return;
  int b = idx >> 16;
  int oc = idx & 65535;
  int o = oc >> 8, c = oc & 255;
  float r0 = rout[b * 768 + c];
  float r1 = rout[b * 768 + 256 + c];
  float r2 = rout[b * 768 + 512 + c];
  const size_t ES = (size_t)256 * 256 * 9;
  const float* w0 = we + ((size_t)o * 256 + c) * 9;
  int ct = c >> 6, c_loc = c & 63;
  int kg = c_loc >> 4, half = (c_loc >> 3) & 1, e = c_loc & 7;
#pragma unroll
  for (int tp = 0; tp < 9; ++tp) {
    float f = r0 * w0[tp] + r1 * w0[ES + tp] + r2 * w0[2 * ES + tp];
    int kt = ct * 9 + tp;
    size_t off = (((size_t)b * 36 + kt) * 8 + kg * 2 + half) * 2048 + o * 8 + e;
    cw[off] = f2bf(f);
  }
}

// ---------------- Kernel D: per-sample implicit-GEMM conv (MFMA 32x32x16 bf16) ----------------
// Block: 512 thr (8 waves, 4m x 2n). Block tile 256 O x 2 rows (120 px).
// Wave tile 64 O x 64 px -> acc = 2x2 f32x16 (64 regs). A read DIRECTLY from global
// (k-major cw2, coalesced 512B segments, 1-tap register prefetch, no A-LDS, no per-tap barrier).
// LDS: X dbuf 2 x [4 rows][64 col][64 c] = 64KB. Barriers: 1 per ct (4 total).
__global__ __launch_bounds__(512, 2) void conv_kernel(const u16* __restrict__ xpad,
                                                      const u16* __restrict__ cw,
                                                      float* __restrict__ y) {
  __shared__ __align__(16) u16 smem[32768];   // 64 KB

  const int flat = blockIdx.x;
  const int wg = (flat & 7) * 120 + (flat >> 3);   // bijective XCD swizzle (960 % 8 == 0)
  const int b = wg / 30;
  const int rg = wg - b * 30;
  const int h0 = rg * 2;

  const int t = threadIdx.x;
  const int wave = t >> 6, lane = t & 63;
  const int wm = wave >> 1, wn = wave & 1;        // 4m x 2n
  const int r32 = lane & 31, half = lane >> 5;

  const u16* cwB = cw + (size_t)b * 589824;        // 36 * 16384
  const u16* xpB = xpad + ((size_t)(b * 62 + h0) * 64) * 256;

  // ---- X staging: 2048 16B-units (512 thr x 4), pre-swizzled global src, linear LDS dst ----
  int x_src[4];
#pragma unroll
  for (int i = 0; i < 4; ++i) {
    int u = i * 512 + t;
    int row = u >> 9, col = (u >> 3) & 63, sd = u & 7;
    int sw = (col ^ (col >> 3)) & 7;
    x_src[i] = (row * 64 + col) * 256 + ((sd ^ sw) * 8);
  }
  // ---- A operand offsets (u16 units within a kt-slab of 16384) ----
  int a_off[2][4];
#pragma unroll
  for (int mf = 0; mf < 2; ++mf)
#pragma unroll
    for (int kg = 0; kg < 4; ++kg)
      a_off[mf][kg] = (kg * 2 + half) * 2048 + (wm * 64 + mf * 32 + r32) * 8;
  // ---- B fragment offsets per (kw, nf) with TRUE column r32 + kw + nf*32 ----
  int b_coff[3][2];
#pragma unroll
  for (int kw = 0; kw < 3; ++kw)
#pragma unroll
    for (int nf = 0; nf < 2; ++nf) {
      int col = r32 + kw + nf * 32;
      int sw = (col ^ (col >> 3)) & 7;
      b_coff[kw][nf] = col * 64 + ((half ^ sw) * 8);
    }

  f32x16 acc[2][2] = {};
  uint4 rA[8];                                     // A(kt) prefetch: 32 VGPRs

  auto loadA = [&](int kt) {
    const u16* base = cwB + (size_t)kt * 16384;
#pragma unroll
    for (int mf = 0; mf < 2; ++mf)
#pragma unroll
      for (int kg = 0; kg < 4; ++kg)
        rA[mf * 4 + kg] = *reinterpret_cast<const uint4*>(base + a_off[mf][kg]);
  };
  auto stageX = [&](int ct, int buf) {
    u16* dst = smem + buf * 16384;
#pragma unroll
    for (int i = 0; i < 4; ++i)
      glds16(xpB + x_src[i] + ct * 64, dst + (i * 512 + t) * 8);
  };

  // ---- prologue ----
  stageX(0, 0);
  loadA(0);
  __syncthreads();                       // drains X(0) DMA

#pragma unroll 1
  for (int ct = 0; ct < 4; ++ct) {
    if (ct < 3) stageX(ct + 1, (ct + 1) & 1);      // issue next X tile DMA now
    const u16* xs = smem + (ct & 1) * 16384;
#pragma unroll
    for (int tap = 0; tap < 9; ++tap) {
      const int kt = ct * 9 + tap;
      // snapshot A(kt) operands (SSA rename; loadA below writes fresh regs)
      bfrag a[2][4];
#pragma unroll
      for (int mf = 0; mf < 2; ++mf)
#pragma unroll
        for (int kg = 0; kg < 4; ++kg)
          a[mf][kg] = __builtin_bit_cast(bfrag, rA[mf * 4 + kg]);
      if (kt + 1 < 36) loadA(kt + 1);    // prefetch next tap, hidden under MFMA
      const int kh = tap / 3, kw = tap - kh * 3;
      const int rowbase = (wn + kh) * 4096;
      __builtin_amdgcn_s_setprio(1);
#pragma unroll
      for (int kg = 0; kg < 4; ++kg) {
        const int kx = kg << 4;
        bfrag bb[2];
#pragma unroll
        for (int nf = 0; nf < 2; ++nf)
          bb[nf] = *reinterpret_cast<const bfrag*>(xs + ((rowbase + b_coff[kw][nf]) ^ kx));
#pragma unroll
        for (int mf = 0; mf < 2; ++mf)
#pragma unroll
          for (int nf = 0; nf < 2; ++nf)
            acc[mf][nf] = __builtin_amdgcn_mfma_f32_32x32x16_bf16(a[mf][kg], bb[nf], acc[mf][nf], 0, 0, 0);
      }
      __builtin_amdgcn_s_setprio(0);
    }
    __syncthreads();                     // X(ct) reads done; X(ct+1) DMA drained
  }

  // ---- epilogue: C/D 32x32: col=lane&31, row=(reg&3)+8*(reg>>2)+4*(lane>>5) ----
  float* yB = y + ((size_t)(b * 256 + wm * 64)) * 3600 + (size_t)(h0 + wn) * 60;
#pragma unroll
  for (int mf = 0; mf < 2; ++mf)
#pragma unroll
    for (int nf = 0; nf < 2; ++nf) {
      int w = nf * 32 + r32;
      if (w < 60) {
#pragma unroll
        for (int g = 0; g < 4; ++g)
#pragma unroll
          for (int rr = 0; rr < 4; ++rr) {
            int o_loc = mf * 32 + g * 8 + half * 4 + rr;
            yB[(size_t)o_loc * 3600 + w] = acc[mf][nf][g * 4 + rr];
          }
      }
    }
}

extern "C" void kernel_launch(void* const* d_in, const int* in_sizes, int n_in,
                              void* d_out, int out_size, void* d_ws, size_t ws_size,
                              hipStream_t stream) {
  const float* x    = (const float*)d_in[0];
  const float* we   = (const float*)d_in[1];
  const float* rw1  = (const float*)d_in[2];
  const float* rdw1 = (const float*)d_in[3];
  const float* rdw2 = (const float*)d_in[4];
  const float* rw2  = (const float*)d_in[5];
  float* y = (float*)d_out;

  char* ws = (char*)d_ws;
  float* att  = (float*)ws;                    // 2,457,600 B
  float* rout = (float*)(ws + 2457600);        //    98,304 B
  u16*   cwp  = (u16*)(ws + 2555904);          // 37,748,736 B
  u16*   xpad = (u16*)(ws + 40304640);         // 65,011,712 B  (total 105,316,352)

  prep_kernel<<<10176, 256, 0, stream>>>(x, xpad, att);
  route_kernel<<<32, 256, 0, stream>>>(att, rw1, rdw1, rdw2, rw2, rout);
  cw_kernel<<<8192, 256, 0, stream>>>(rout, we, cwp);
  conv_kernel<<<960, 512, 0, stream>>>(xpad, cwp, y);
  (void)in_sizes; (void)n_in; (void)out_size; (void)ws_size;
}